// Round 7
// baseline (786.514 us; speedup 1.0000x reference)
//
#include <hip/hip_runtime.h>

typedef _Float16 half8 __attribute__((ext_vector_type(8)));
typedef _Float16 half4 __attribute__((ext_vector_type(4)));
typedef __fp16  fp16x2 __attribute__((ext_vector_type(2)));
typedef float f32x4 __attribute__((ext_vector_type(4)));
typedef float f32x16 __attribute__((ext_vector_type(16)));

#define NPB 128       // points per block
#define THREADS 512   // 8 waves: 4 feat-quarters (64 feats) x 2 point-halves (64 pts)
#define INV2PI 0.15915494309189535f
#define W0SCALE (30.0f * INV2PI)
#define SMEM_BYTES (65536 + 384*4 + 256*4)   // hbuf + xs + wf_s = 68096 -> 2 blocks/CU

// hbuf layout, XOR-swizzled, stride 256 (no pad):
//   logical (pt, k): chunk g = k>>3, stored f16 idx = pt*256 + ((g ^ (pt&7))<<3) + (k&7)
// B-reads, epilogue stores, layer0 stores, final reads all hit the conflict-free
// bank minimum by construction (8 dw/bank for b128, 4 for b64).

__device__ __forceinline__ half4 pk4(float a, float b, float c, float d) {
    fp16x2 lo = __builtin_amdgcn_cvt_pkrtz(a, b);
    fp16x2 hi = __builtin_amdgcn_cvt_pkrtz(c, d);
    half4 r;
    r[0] = (_Float16)lo[0]; r[1] = (_Float16)lo[1];
    r[2] = (_Float16)hi[0]; r[3] = (_Float16)hi[1];
    return r;
}

// Repack W1..W4 fp32 [256x256] row-major -> f16 chunk-major [kc][n][kl] (kc=k/32, kl=k%32),
// PRESCALED by 1/(2*pi) so the epilogue sine is a bare v_sin_f32 (input in revolutions).
__global__ void convert_weights(const float* __restrict__ W1, const float* __restrict__ W2,
                                const float* __restrict__ W3, const float* __restrict__ W4,
                                _Float16* __restrict__ Wc) {
    int tid = blockIdx.x * 256 + threadIdx.x;      // 0 .. 262143
    int l   = tid >> 16;
    int rem = tid & 65535;
    int n = rem >> 8, k = rem & 255;
    const float* W = (l == 0) ? W1 : (l == 1) ? W2 : (l == 2) ? W3 : W4;
    int kc = k >> 5, kl = k & 31;
    Wc[l * 65536 + kc * 8192 + n * 32 + kl] = (_Float16)(W[rem] * INV2PI);
}

__launch_bounds__(THREADS, 4)
__global__ void siren_fused(const float* __restrict__ xyt,
                            const float* __restrict__ W0,
                            const float* __restrict__ b0,
                            const _Float16* __restrict__ Wc,
                            const float* __restrict__ b1,
                            const float* __restrict__ b2,
                            const float* __restrict__ b3,
                            const float* __restrict__ b4,
                            const float* __restrict__ Wf,
                            const float* __restrict__ bfin,
                            float* __restrict__ out)
{
    extern __shared__ _Float16 smem[];
    _Float16* hbuf = smem;                           // 32768 f16 = 64 KB
    float* xs   = (float*)(smem + 32768);            // 384 f32
    float* wf_s = xs + 384;                          // 256 f32

    const int tid  = threadIdx.x;
    const int lane = tid & 63;
    const int wv   = tid >> 6;
    const int fq   = wv & 3;         // feature quarter: feats [fq*64, fq*64+64)
    const int ph   = wv >> 2;        // point half:      pts   [ph*64, ph*64+64)
    const int l31  = lane & 31;
    const int o4   = lane >> 5;      // 0/1
    const int l7   = lane & 7;
    const int gm0  = blockIdx.x * NPB;

    if (tid < 384) xs[tid] = xyt[gm0 * 3 + tid];
    if (tid < 256) wf_s[tid] = Wf[tid];
    __syncthreads();

    // ---- layer 0: h = sin(30*(x @ W0^T + b0)); prescaled -> bare v_sin; swizzled b64 writes ----
    {
        const int fg = lane;          // features 4*lane .. 4*lane+3
        const int p0 = wv * 16;       // this wave's 16 points
        float w[4][3], bb[4];
        #pragma unroll
        for (int c = 0; c < 4; ++c) {
            const int n = fg * 4 + c;
            w[c][0] = W0[n * 3 + 0] * W0SCALE;
            w[c][1] = W0[n * 3 + 1] * W0SCALE;
            w[c][2] = W0[n * 3 + 2] * W0SCALE;
            bb[c]   = b0[n] * W0SCALE;
        }
        #pragma unroll 4
        for (int p = 0; p < 16; ++p) {
            const int pt = p0 + p;
            const float x0 = xs[pt * 3], x1 = xs[pt * 3 + 1], x2 = xs[pt * 3 + 2];
            float z0 = fmaf(w[0][0], x0, fmaf(w[0][1], x1, fmaf(w[0][2], x2, bb[0])));
            float z1 = fmaf(w[1][0], x0, fmaf(w[1][1], x1, fmaf(w[1][2], x2, bb[1])));
            float z2 = fmaf(w[2][0], x0, fmaf(w[2][1], x1, fmaf(w[2][2], x2, bb[2])));
            float z3 = fmaf(w[3][0], x0, fmaf(w[3][1], x1, fmaf(w[3][2], x2, bb[3])));
            half4 hv = pk4(__builtin_amdgcn_sinf(z0), __builtin_amdgcn_sinf(z1),
                           __builtin_amdgcn_sinf(z2), __builtin_amdgcn_sinf(z3));
            *(half4*)&hbuf[pt * 256 + (((fg >> 1) ^ (pt & 7)) << 3) + (fg & 1) * 4] = hv;
        }
    }

    // ---- per-lane constants for the MFMA phase ----
    const int m8  = (l7 & ~1) | (o4 ^ (l7 & 1));    // chunk 2ks+o4 -> stored 2ks ^ m8
    const int vb0 = (ph * 64 + l31) * 256;          // j=0 point row base (f16 idx)
    const int vb1 = vb0 + 32 * 256;                 // j=1
    const int ar0 = (fq * 64 + l31) * 32 + o4 * 8;  // A rows fq*64+i*32+l31, k-off o4*8
    const int ar1 = ar0 + 32 * 32;

    // A-ring: ksteps (K=16 each), depth 4, 2 feat-tiles -> 32 VGPR
    half8 ring[4][2];
    {
        const _Float16* wl = Wc;
        #pragma unroll
        for (int s = 0; s < 4; ++s) {
            ring[s][0] = *(const half8*)&wl[(s >> 1) * 8192 + (s & 1) * 16 + ar0];
            ring[s][1] = *(const half8*)&wl[(s >> 1) * 8192 + (s & 1) * 16 + ar1];
        }
    }

    // ---- 4 hidden layers: D[feat][pt] = W' h^T, mfma 32x32x16, sin via v_sin ----
    #pragma unroll
    for (int l = 0; l < 4; ++l) {
        const float* bl = (l == 0) ? b1 : (l == 1) ? b2 : (l == 2) ? b3 : b4;
        const _Float16* wl = Wc + l * 65536;

        // bias folded into acc init (prescaled). C/D 32x32: col=lane&31 (pt),
        // row = (reg&3) + 8*(reg>>2) + 4*o4 ; feat = fq*64 + i*32 + row
        f32x16 acc[2][2];
        #pragma unroll
        for (int i = 0; i < 2; ++i) {
            #pragma unroll
            for (int q = 0; q < 4; ++q) {
                f32x4 bb = *(const f32x4*)&bl[fq * 64 + i * 32 + q * 8 + o4 * 4];
                bb *= INV2PI;
                #pragma unroll
                for (int r = 0; r < 4; ++r) {
                    acc[i][0][q * 4 + r] = bb[r];
                    acc[i][1][q * 4 + r] = bb[r];
                }
            }
        }

        __syncthreads();   // hbuf from previous layer stable

        #pragma unroll
        for (int ks = 0; ks < 16; ++ks) {
            half8 a0 = ring[ks & 3][0];
            half8 a1 = ring[ks & 3][1];
            if (ks < 12) {
                ring[ks & 3][0] = *(const half8*)&wl[((ks + 4) >> 1) * 8192 + ((ks + 4) & 1) * 16 + ar0];
                ring[ks & 3][1] = *(const half8*)&wl[((ks + 4) >> 1) * 8192 + ((ks + 4) & 1) * 16 + ar1];
            }
            const int boff = ((2 * ks) ^ m8) << 3;
            half8 b0f = *(const half8*)&hbuf[vb0 + boff];
            half8 b1f = *(const half8*)&hbuf[vb1 + boff];
            acc[0][0] = __builtin_amdgcn_mfma_f32_32x32x16_f16(a0, b0f, acc[0][0], 0, 0, 0);
            acc[0][1] = __builtin_amdgcn_mfma_f32_32x32x16_f16(a0, b1f, acc[0][1], 0, 0, 0);
            acc[1][0] = __builtin_amdgcn_mfma_f32_32x32x16_f16(a1, b0f, acc[1][0], 0, 0, 0);
            acc[1][1] = __builtin_amdgcn_mfma_f32_32x32x16_f16(a1, b1f, acc[1][1], 0, 0, 0);
        }

        // next layer's ring prologue: global loads issued before barrier + epilogue math
        if (l < 3) {
            const _Float16* wn = wl + 65536;
            #pragma unroll
            for (int s = 0; s < 4; ++s) {
                ring[s][0] = *(const half8*)&wn[(s >> 1) * 8192 + (s & 1) * 16 + ar0];
                ring[s][1] = *(const half8*)&wn[(s >> 1) * 8192 + (s & 1) * 16 + ar1];
            }
        }

        __syncthreads();   // all waves' B-reads done -> safe to overwrite hbuf

        // Epilogue: per (i,j,q): 4 consecutive feats at base fq*64+i*32+q*8+o4*4,
        // pt = ph*64 + j*32 + l31; swizzled half4 store.
        #pragma unroll
        for (int i = 0; i < 2; ++i)
            #pragma unroll
            for (int j = 0; j < 2; ++j) {
                const int pt = ph * 64 + j * 32 + l31;
                #pragma unroll
                for (int q = 0; q < 4; ++q) {
                    half4 hv = pk4(__builtin_amdgcn_sinf(acc[i][j][q * 4 + 0]),
                                   __builtin_amdgcn_sinf(acc[i][j][q * 4 + 1]),
                                   __builtin_amdgcn_sinf(acc[i][j][q * 4 + 2]),
                                   __builtin_amdgcn_sinf(acc[i][j][q * 4 + 3]));
                    const int g = fq * 8 + i * 4 + q;
                    *(half4*)&hbuf[pt * 256 + ((g ^ l7) << 3) + o4 * 4] = hv;
                }
            }
    }

    __syncthreads();   // final hbuf visible

    // ---- final layer: out[m] = h[m,:] . Wf + bf, 4 lanes per point ----
    {
        const int m = tid >> 2, q = tid & 3;
        float sum = 0.f;
        #pragma unroll
        for (int i = 0; i < 8; ++i) {
            half8 hv = *(const half8*)&hbuf[m * 256 + (((q * 8 + i) ^ (m & 7)) << 3)];
            const int nb = q * 64 + i * 8;
            #pragma unroll
            for (int jj = 0; jj < 8; ++jj)
                sum = fmaf((float)hv[jj], wf_s[nb + jj], sum);
        }
        sum += __shfl_down(sum, 2);
        sum += __shfl_down(sum, 1);
        if (q == 0) out[gm0 + m] = sum + bfin[0];
    }
}

extern "C" void kernel_launch(void* const* d_in, const int* in_sizes, int n_in,
                              void* d_out, int out_size, void* d_ws, size_t ws_size,
                              hipStream_t stream) {
    const float* xyt = (const float*)d_in[0];
    const float* W0  = (const float*)d_in[1];
    const float* b0  = (const float*)d_in[2];
    const float* W1  = (const float*)d_in[3];
    const float* b1  = (const float*)d_in[4];
    const float* W2  = (const float*)d_in[5];
    const float* b2  = (const float*)d_in[6];
    const float* W3  = (const float*)d_in[7];
    const float* b3  = (const float*)d_in[8];
    const float* W4  = (const float*)d_in[9];
    const float* b4  = (const float*)d_in[10];
    const float* Wf  = (const float*)d_in[11];
    const float* bf  = (const float*)d_in[12];
    float* out = (float*)d_out;
    _Float16* Wc = (_Float16*)d_ws;    // 4 * 65536 f16 = 512 KB

    (void)hipFuncSetAttribute((const void*)siren_fused,
                        hipFuncAttributeMaxDynamicSharedMemorySize, SMEM_BYTES);

    convert_weights<<<1024, 256, 0, stream>>>(W1, W2, W3, W4, Wc);

    const int N = in_sizes[0] / 3;     // 1048576
    siren_fused<<<N / NPB, THREADS, SMEM_BYTES, stream>>>(
        xyt, W0, b0, Wc, b1, b2, b3, b4, Wf, bf, out);
}

// Round 8
// 733.679 us; speedup vs baseline: 1.0720x; 1.0720x over previous
//
#include <hip/hip_runtime.h>

typedef _Float16 half8 __attribute__((ext_vector_type(8)));
typedef _Float16 half4 __attribute__((ext_vector_type(4)));
typedef __fp16  fp16x2 __attribute__((ext_vector_type(2)));
typedef float f32x4 __attribute__((ext_vector_type(4)));
typedef float f32x16 __attribute__((ext_vector_type(16)));

#define NPB 128       // points per block
#define THREADS 512   // 8 waves: 4 feat-quarters (64 feats) x 2 point-halves (64 pts)
#define INV2PI 0.15915494309189535f
#define W0SCALE (30.0f * INV2PI)
#define SMEM_BYTES (65536 + 384*4 + 256*4)   // hbuf + xs + wf_s = 68096 -> 2 blocks/CU

// hbuf layout, XOR-swizzled, stride 256 (no pad):
//   logical (pt, k): chunk g = k>>3, stored f16 idx = pt*256 + ((g ^ (pt&7))<<3) + (k&7)
// All LDS access sites hit the conflict-free bank minimum (verified R7: absmax ok,
// conflicts down 30%). R7's regression was register SPILL (WRITE_SIZE 300 MB);
// this version trims the A-ring to depth 2 to fit 64 VGPR + 64 AGPR exactly.

__device__ __forceinline__ half4 pk4(float a, float b, float c, float d) {
    fp16x2 lo = __builtin_amdgcn_cvt_pkrtz(a, b);
    fp16x2 hi = __builtin_amdgcn_cvt_pkrtz(c, d);
    half4 r;
    r[0] = (_Float16)lo[0]; r[1] = (_Float16)lo[1];
    r[2] = (_Float16)hi[0]; r[3] = (_Float16)hi[1];
    return r;
}

// Repack W1..W4 fp32 [256x256] row-major -> f16 chunk-major [kc][n][kl] (kc=k/32, kl=k%32),
// PRESCALED by 1/(2*pi) so the epilogue sine is a bare v_sin_f32 (input in revolutions).
__global__ void convert_weights(const float* __restrict__ W1, const float* __restrict__ W2,
                                const float* __restrict__ W3, const float* __restrict__ W4,
                                _Float16* __restrict__ Wc) {
    int tid = blockIdx.x * 256 + threadIdx.x;      // 0 .. 262143
    int l   = tid >> 16;
    int rem = tid & 65535;
    int n = rem >> 8, k = rem & 255;
    const float* W = (l == 0) ? W1 : (l == 1) ? W2 : (l == 2) ? W3 : W4;
    int kc = k >> 5, kl = k & 31;
    Wc[l * 65536 + kc * 8192 + n * 32 + kl] = (_Float16)(W[rem] * INV2PI);
}

__launch_bounds__(THREADS, 4)
__global__ void siren_fused(const float* __restrict__ xyt,
                            const float* __restrict__ W0,
                            const float* __restrict__ b0,
                            const _Float16* __restrict__ Wc,
                            const float* __restrict__ b1,
                            const float* __restrict__ b2,
                            const float* __restrict__ b3,
                            const float* __restrict__ b4,
                            const float* __restrict__ Wf,
                            const float* __restrict__ bfin,
                            float* __restrict__ out)
{
    extern __shared__ _Float16 smem[];
    _Float16* hbuf = smem;                           // 32768 f16 = 64 KB
    float* xs   = (float*)(smem + 32768);            // 384 f32
    float* wf_s = xs + 384;                          // 256 f32

    const int tid  = threadIdx.x;
    const int lane = tid & 63;
    const int wv   = tid >> 6;
    const int fq   = wv & 3;         // feature quarter: feats [fq*64, fq*64+64)
    const int ph   = wv >> 2;        // point half:      pts   [ph*64, ph*64+64)
    const int l31  = lane & 31;
    const int o4   = lane >> 5;      // 0/1
    const int l7   = lane & 7;
    const int gm0  = blockIdx.x * NPB;

    if (tid < 384) xs[tid] = xyt[gm0 * 3 + tid];
    if (tid < 256) wf_s[tid] = Wf[tid];
    __syncthreads();

    // ---- layer 0: h = sin(30*(x @ W0^T + b0)); prescaled -> bare v_sin; swizzled b64 writes ----
    {
        const int fg = lane;          // features 4*lane .. 4*lane+3
        const int p0 = wv * 16;       // this wave's 16 points
        float w[4][3], bb[4];
        #pragma unroll
        for (int c = 0; c < 4; ++c) {
            const int n = fg * 4 + c;
            w[c][0] = W0[n * 3 + 0] * W0SCALE;
            w[c][1] = W0[n * 3 + 1] * W0SCALE;
            w[c][2] = W0[n * 3 + 2] * W0SCALE;
            bb[c]   = b0[n] * W0SCALE;
        }
        #pragma unroll 4
        for (int p = 0; p < 16; ++p) {
            const int pt = p0 + p;
            const float x0 = xs[pt * 3], x1 = xs[pt * 3 + 1], x2 = xs[pt * 3 + 2];
            float z0 = fmaf(w[0][0], x0, fmaf(w[0][1], x1, fmaf(w[0][2], x2, bb[0])));
            float z1 = fmaf(w[1][0], x0, fmaf(w[1][1], x1, fmaf(w[1][2], x2, bb[1])));
            float z2 = fmaf(w[2][0], x0, fmaf(w[2][1], x1, fmaf(w[2][2], x2, bb[2])));
            float z3 = fmaf(w[3][0], x0, fmaf(w[3][1], x1, fmaf(w[3][2], x2, bb[3])));
            half4 hv = pk4(__builtin_amdgcn_sinf(z0), __builtin_amdgcn_sinf(z1),
                           __builtin_amdgcn_sinf(z2), __builtin_amdgcn_sinf(z3));
            *(half4*)&hbuf[pt * 256 + (((fg >> 1) ^ (pt & 7)) << 3) + (fg & 1) * 4] = hv;
        }
    }

    // ---- per-lane constants for the MFMA phase ----
    const int m8  = (l7 & ~1) | (o4 ^ (l7 & 1));    // chunk 2ks+o4 -> stored 2ks ^ m8
    const int vb0 = (ph * 64 + l31) * 256;          // j=0 point row base (f16 idx)
    const int vb1 = vb0 + 32 * 256;                 // j=1
    const int ar0 = (fq * 64 + l31) * 32 + o4 * 8;  // A rows fq*64+i*32+l31, k-off o4*8
    const int ar1 = ar0 + 32 * 32;

    // A-ring: depth 2 (16 VGPR), prefetch distance 2 ksteps (~250 cyc, L2-warm ~200)
    half8 ring[2][2];
    {
        const _Float16* wl = Wc;
        #pragma unroll
        for (int s = 0; s < 2; ++s) {
            ring[s][0] = *(const half8*)&wl[(s >> 1) * 8192 + (s & 1) * 16 + ar0];
            ring[s][1] = *(const half8*)&wl[(s >> 1) * 8192 + (s & 1) * 16 + ar1];
        }
    }

    // ---- 4 hidden layers: D[feat][pt] = W' h^T, mfma 32x32x16, sin via v_sin ----
    #pragma unroll
    for (int l = 0; l < 4; ++l) {
        const float* bl = (l == 0) ? b1 : (l == 1) ? b2 : (l == 2) ? b3 : b4;
        const _Float16* wl = Wc + l * 65536;

        // bias folded into acc init (prescaled). C/D 32x32: col=lane&31 (pt),
        // row = (reg&3) + 8*(reg>>2) + 4*o4 ; feat = fq*64 + i*32 + row
        f32x16 acc[2][2];
        #pragma unroll
        for (int i = 0; i < 2; ++i) {
            #pragma unroll
            for (int q = 0; q < 4; ++q) {
                f32x4 bb = *(const f32x4*)&bl[fq * 64 + i * 32 + q * 8 + o4 * 4];
                bb *= INV2PI;
                #pragma unroll
                for (int r = 0; r < 4; ++r) {
                    acc[i][0][q * 4 + r] = bb[r];
                    acc[i][1][q * 4 + r] = bb[r];
                }
            }
        }

        __syncthreads();   // hbuf from previous layer stable

        #pragma unroll
        for (int ks = 0; ks < 16; ++ks) {
            const int boff = ((2 * ks) ^ m8) << 3;
            half8 b0f = *(const half8*)&hbuf[vb0 + boff];
            half8 b1f = *(const half8*)&hbuf[vb1 + boff];
            acc[0][0] = __builtin_amdgcn_mfma_f32_32x32x16_f16(ring[ks & 1][0], b0f, acc[0][0], 0, 0, 0);
            acc[0][1] = __builtin_amdgcn_mfma_f32_32x32x16_f16(ring[ks & 1][0], b1f, acc[0][1], 0, 0, 0);
            acc[1][0] = __builtin_amdgcn_mfma_f32_32x32x16_f16(ring[ks & 1][1], b0f, acc[1][0], 0, 0, 0);
            acc[1][1] = __builtin_amdgcn_mfma_f32_32x32x16_f16(ring[ks & 1][1], b1f, acc[1][1], 0, 0, 0);
            // refill the slot just consumed with kstep ks+2 (issued after its last use,
            // so no live copy is needed); last two iters load next layer's ks=0,1
            if (ks < 14) {
                ring[ks & 1][0] = *(const half8*)&wl[((ks + 2) >> 1) * 8192 + ((ks + 2) & 1) * 16 + ar0];
                ring[ks & 1][1] = *(const half8*)&wl[((ks + 2) >> 1) * 8192 + ((ks + 2) & 1) * 16 + ar1];
            } else if (l < 3) {
                const _Float16* wn = wl + 65536;
                const int s = ks - 14;   // 0,1 -> next layer chunks 0,1
                ring[s][0] = *(const half8*)&wn[(s & 1) * 16 + ar0];
                ring[s][1] = *(const half8*)&wn[(s & 1) * 16 + ar1];
            }
        }

        __syncthreads();   // all waves' B-reads done -> safe to overwrite hbuf

        // Epilogue: per (i,j,q): 4 consecutive feats at base fq*64+i*32+q*8+o4*4,
        // pt = ph*64 + j*32 + l31; swizzled half4 store.
        #pragma unroll
        for (int i = 0; i < 2; ++i)
            #pragma unroll
            for (int j = 0; j < 2; ++j) {
                const int pt = ph * 64 + j * 32 + l31;
                #pragma unroll
                for (int q = 0; q < 4; ++q) {
                    half4 hv = pk4(__builtin_amdgcn_sinf(acc[i][j][q * 4 + 0]),
                                   __builtin_amdgcn_sinf(acc[i][j][q * 4 + 1]),
                                   __builtin_amdgcn_sinf(acc[i][j][q * 4 + 2]),
                                   __builtin_amdgcn_sinf(acc[i][j][q * 4 + 3]));
                    const int g = fq * 8 + i * 4 + q;
                    *(half4*)&hbuf[pt * 256 + ((g ^ l7) << 3) + o4 * 4] = hv;
                }
            }
    }

    __syncthreads();   // final hbuf visible

    // ---- final layer: out[m] = h[m,:] . Wf + bf, 4 lanes per point ----
    {
        const int m = tid >> 2, q = tid & 3;
        float sum = 0.f;
        #pragma unroll
        for (int i = 0; i < 8; ++i) {
            half8 hv = *(const half8*)&hbuf[m * 256 + (((q * 8 + i) ^ (m & 7)) << 3)];
            const int nb = q * 64 + i * 8;
            #pragma unroll
            for (int jj = 0; jj < 8; ++jj)
                sum = fmaf((float)hv[jj], wf_s[nb + jj], sum);
        }
        sum += __shfl_down(sum, 2);
        sum += __shfl_down(sum, 1);
        if (q == 0) out[gm0 + m] = sum + bfin[0];
    }
}

extern "C" void kernel_launch(void* const* d_in, const int* in_sizes, int n_in,
                              void* d_out, int out_size, void* d_ws, size_t ws_size,
                              hipStream_t stream) {
    const float* xyt = (const float*)d_in[0];
    const float* W0  = (const float*)d_in[1];
    const float* b0  = (const float*)d_in[2];
    const float* W1  = (const float*)d_in[3];
    const float* b1  = (const float*)d_in[4];
    const float* W2  = (const float*)d_in[5];
    const float* b2  = (const float*)d_in[6];
    const float* W3  = (const float*)d_in[7];
    const float* b3  = (const float*)d_in[8];
    const float* W4  = (const float*)d_in[9];
    const float* b4  = (const float*)d_in[10];
    const float* Wf  = (const float*)d_in[11];
    const float* bf  = (const float*)d_in[12];
    float* out = (float*)d_out;
    _Float16* Wc = (_Float16*)d_ws;    // 4 * 65536 f16 = 512 KB

    (void)hipFuncSetAttribute((const void*)siren_fused,
                        hipFuncAttributeMaxDynamicSharedMemorySize, SMEM_BYTES);

    convert_weights<<<1024, 256, 0, stream>>>(W1, W2, W3, W4, Wc);

    const int N = in_sizes[0] / 3;     // 1048576
    siren_fused<<<N / NPB, THREADS, SMEM_BYTES, stream>>>(
        xyt, W0, b0, Wc, b1, b2, b3, b4, Wf, bf, out);
}

// Round 9
// 695.559 us; speedup vs baseline: 1.1308x; 1.0548x over previous
//
#include <hip/hip_runtime.h>

typedef _Float16 half8 __attribute__((ext_vector_type(8)));
typedef _Float16 half4 __attribute__((ext_vector_type(4)));
typedef __fp16  fp16x2 __attribute__((ext_vector_type(2)));
typedef float f32x4 __attribute__((ext_vector_type(4)));
typedef float f32x16 __attribute__((ext_vector_type(16)));

#define NPB 64        // points per block
#define THREADS 256   // 4 waves; wave wv owns feats [wv*64, wv*64+64) x all 64 pts
#define INV2PI 0.15915494309189535f
#define W0SCALE (30.0f * INV2PI)

// hbuf: XOR-swizzled, stride 256 f16 (no pad):
//   (pt, k) -> pt*256 + (((k>>3) ^ (pt&7))<<3) + (k&7)
// All LDS sites at the wide-access bank minimum (verified R7/R8: absmax ok).
// R8 post-mortem: wall = 3.2x MFMA floor from pipe gaps, not pipe saturation.
// This version: 4 independent 4-wave blocks/CU (phase diversity) + manual
// B double-buffer so lgkmcnt waits land after the MFMA burst.

__device__ __forceinline__ half4 pk4(float a, float b, float c, float d) {
    fp16x2 lo = __builtin_amdgcn_cvt_pkrtz(a, b);
    fp16x2 hi = __builtin_amdgcn_cvt_pkrtz(c, d);
    half4 r;
    r[0] = (_Float16)lo[0]; r[1] = (_Float16)lo[1];
    r[2] = (_Float16)hi[0]; r[3] = (_Float16)hi[1];
    return r;
}

// Repack W1..W4 fp32 [256x256] -> f16 chunk-major [kc][n][kl], prescaled by 1/(2pi)
// so layer sine is a bare v_sin_f32 (revolutions).
__global__ void convert_weights(const float* __restrict__ W1, const float* __restrict__ W2,
                                const float* __restrict__ W3, const float* __restrict__ W4,
                                _Float16* __restrict__ Wc) {
    int tid = blockIdx.x * 256 + threadIdx.x;      // 0 .. 262143
    int l   = tid >> 16;
    int rem = tid & 65535;
    int n = rem >> 8, k = rem & 255;
    const float* W = (l == 0) ? W1 : (l == 1) ? W2 : (l == 2) ? W3 : W4;
    int kc = k >> 5, kl = k & 31;
    Wc[l * 65536 + kc * 8192 + n * 32 + kl] = (_Float16)(W[rem] * INV2PI);
}

__launch_bounds__(THREADS, 4)
__global__ void siren_fused(const float* __restrict__ xyt,
                            const float* __restrict__ W0,
                            const float* __restrict__ b0,
                            const _Float16* __restrict__ Wc,
                            const float* __restrict__ b1,
                            const float* __restrict__ b2,
                            const float* __restrict__ b3,
                            const float* __restrict__ b4,
                            const float* __restrict__ Wf,
                            const float* __restrict__ bfin,
                            float* __restrict__ out)
{
    __shared__ _Float16 hbuf[NPB * 256];   // 32 KB
    __shared__ float    xs[NPB * 3];
    __shared__ float    wf_s[256];

    const int tid  = threadIdx.x;
    const int lane = tid & 63;
    const int wv   = tid >> 6;       // 0..3
    const int l31  = lane & 31;
    const int o4   = lane >> 5;      // 0/1
    const int l7   = lane & 7;
    const int gm0  = blockIdx.x * NPB;

    if (tid < NPB * 3) xs[tid] = xyt[gm0 * 3 + tid];
    wf_s[tid] = Wf[tid];
    __syncthreads();

    // ---- per-lane constants ----
    const int m8  = (l7 & ~1) | (o4 ^ (l7 & 1));    // chunk 2ks+o4 stored as 2ks ^ m8
    const int vb0 = l31 * 256;                      // pt row base, j=0
    const int vb1 = vb0 + 32 * 256;                 // j=1
    const int ar0 = (wv * 64 + l31) * 32 + o4 * 8;  // A row base (feat tile i=0)
    const int ar1 = ar0 + 32 * 32;                  // i=1

    // A-ring prologue for layer 0 (issued early; covered by layer-0 VALU work)
    half8 ring[2][2];
    #pragma unroll
    for (int s = 0; s < 2; ++s) {
        ring[s][0] = *(const half8*)&Wc[s * 16 + ar0];
        ring[s][1] = *(const half8*)&Wc[s * 16 + ar1];
    }

    // ---- layer 0: h = sin(30*(x @ W0^T + b0)); swizzled b64 writes ----
    {
        const int fg = lane;          // features 4*lane .. 4*lane+3
        const int p0 = wv * 16;       // this wave's 16 points
        float w[4][3], bb[4];
        #pragma unroll
        for (int c = 0; c < 4; ++c) {
            const int n = fg * 4 + c;
            w[c][0] = W0[n * 3 + 0] * W0SCALE;
            w[c][1] = W0[n * 3 + 1] * W0SCALE;
            w[c][2] = W0[n * 3 + 2] * W0SCALE;
            bb[c]   = b0[n] * W0SCALE;
        }
        #pragma unroll 4
        for (int p = 0; p < 16; ++p) {
            const int pt = p0 + p;
            const float x0 = xs[pt * 3], x1 = xs[pt * 3 + 1], x2 = xs[pt * 3 + 2];
            float z0 = fmaf(w[0][0], x0, fmaf(w[0][1], x1, fmaf(w[0][2], x2, bb[0])));
            float z1 = fmaf(w[1][0], x0, fmaf(w[1][1], x1, fmaf(w[1][2], x2, bb[1])));
            float z2 = fmaf(w[2][0], x0, fmaf(w[2][1], x1, fmaf(w[2][2], x2, bb[2])));
            float z3 = fmaf(w[3][0], x0, fmaf(w[3][1], x1, fmaf(w[3][2], x2, bb[3])));
            half4 hv = pk4(__builtin_amdgcn_sinf(z0), __builtin_amdgcn_sinf(z1),
                           __builtin_amdgcn_sinf(z2), __builtin_amdgcn_sinf(z3));
            *(half4*)&hbuf[pt * 256 + (((fg >> 1) ^ (pt & 7)) << 3) + (fg & 1) * 4] = hv;
        }
    }

    // ---- 4 hidden layers: D[feat][pt] = W' h^T, mfma 32x32x16 ----
    #pragma unroll
    for (int l = 0; l < 4; ++l) {
        const float* bl = (l == 0) ? b1 : (l == 1) ? b2 : (l == 2) ? b3 : b4;
        const _Float16* wl = Wc + l * 65536;

        // bias folded into acc init (prescaled); issued before the barrier.
        // C/D 32x32: col=lane&31 (pt), row=(reg&3)+8*(reg>>2)+4*o4; feat=wv*64+i*32+row
        f32x16 acc[2][2];
        #pragma unroll
        for (int i = 0; i < 2; ++i) {
            #pragma unroll
            for (int q = 0; q < 4; ++q) {
                f32x4 bb = *(const f32x4*)&bl[wv * 64 + i * 32 + q * 8 + o4 * 4];
                bb *= INV2PI;
                #pragma unroll
                for (int r = 0; r < 4; ++r) {
                    acc[i][0][q * 4 + r] = bb[r];
                    acc[i][1][q * 4 + r] = bb[r];
                }
            }
        }

        __syncthreads();   // hbuf from previous layer stable

        // B double-buffer: current kstep's frags loaded one iteration ahead,
        // so each kstep's lgkmcnt wait sits behind 4 MFMAs of issue.
        half8 b0c = *(const half8*)&hbuf[vb0 + ((0 ^ m8) << 3)];
        half8 b1c = *(const half8*)&hbuf[vb1 + ((0 ^ m8) << 3)];

        #pragma unroll
        for (int ks = 0; ks < 16; ++ks) {
            half8 b0n, b1n;
            if (ks < 15) {
                const int boff = ((2 * (ks + 1)) ^ m8) << 3;
                b0n = *(const half8*)&hbuf[vb0 + boff];
                b1n = *(const half8*)&hbuf[vb1 + boff];
            }
            acc[0][0] = __builtin_amdgcn_mfma_f32_32x32x16_f16(ring[ks & 1][0], b0c, acc[0][0], 0, 0, 0);
            acc[0][1] = __builtin_amdgcn_mfma_f32_32x32x16_f16(ring[ks & 1][0], b1c, acc[0][1], 0, 0, 0);
            acc[1][0] = __builtin_amdgcn_mfma_f32_32x32x16_f16(ring[ks & 1][1], b0c, acc[1][0], 0, 0, 0);
            acc[1][1] = __builtin_amdgcn_mfma_f32_32x32x16_f16(ring[ks & 1][1], b1c, acc[1][1], 0, 0, 0);
            // refill consumed ring slot with kstep ks+2; last two iters preload next layer
            if (ks < 14) {
                ring[ks & 1][0] = *(const half8*)&wl[((ks + 2) >> 1) * 8192 + ((ks + 2) & 1) * 16 + ar0];
                ring[ks & 1][1] = *(const half8*)&wl[((ks + 2) >> 1) * 8192 + ((ks + 2) & 1) * 16 + ar1];
            } else if (l < 3) {
                const _Float16* wn = wl + 65536;
                const int s = ks - 14;
                ring[s][0] = *(const half8*)&wn[s * 16 + ar0];
                ring[s][1] = *(const half8*)&wn[s * 16 + ar1];
            }
            b0c = b0n; b1c = b1n;
        }

        __syncthreads();   // all waves' B-reads done -> safe to overwrite hbuf

        // Epilogue: 4 consecutive feats per reg quad; pt = j*32 + l31.
        #pragma unroll
        for (int i = 0; i < 2; ++i)
            #pragma unroll
            for (int j = 0; j < 2; ++j) {
                const int pt = j * 32 + l31;
                #pragma unroll
                for (int q = 0; q < 4; ++q) {
                    half4 hv = pk4(__builtin_amdgcn_sinf(acc[i][j][q * 4 + 0]),
                                   __builtin_amdgcn_sinf(acc[i][j][q * 4 + 1]),
                                   __builtin_amdgcn_sinf(acc[i][j][q * 4 + 2]),
                                   __builtin_amdgcn_sinf(acc[i][j][q * 4 + 3]));
                    const int g = wv * 8 + i * 4 + q;   // feat-chunk index
                    *(half4*)&hbuf[pt * 256 + ((g ^ l7) << 3) + o4 * 4] = hv;
                }
            }
    }

    __syncthreads();   // final hbuf visible

    // ---- final layer: out[m] = h[m,:] . Wf + bf, 4 lanes per point ----
    {
        const int m = tid >> 2, q = tid & 3;
        float sum = 0.f;
        #pragma unroll
        for (int i = 0; i < 8; ++i) {
            half8 hv = *(const half8*)&hbuf[m * 256 + (((q * 8 + i) ^ (m & 7)) << 3)];
            const int nb = q * 64 + i * 8;
            #pragma unroll
            for (int jj = 0; jj < 8; ++jj)
                sum = fmaf((float)hv[jj], wf_s[nb + jj], sum);
        }
        sum += __shfl_down(sum, 2);
        sum += __shfl_down(sum, 1);
        if (q == 0) out[gm0 + m] = sum + bfin[0];
    }
}

extern "C" void kernel_launch(void* const* d_in, const int* in_sizes, int n_in,
                              void* d_out, int out_size, void* d_ws, size_t ws_size,
                              hipStream_t stream) {
    const float* xyt = (const float*)d_in[0];
    const float* W0  = (const float*)d_in[1];
    const float* b0  = (const float*)d_in[2];
    const float* W1  = (const float*)d_in[3];
    const float* b1  = (const float*)d_in[4];
    const float* W2  = (const float*)d_in[5];
    const float* b2  = (const float*)d_in[6];
    const float* W3  = (const float*)d_in[7];
    const float* b3  = (const float*)d_in[8];
    const float* W4  = (const float*)d_in[9];
    const float* b4  = (const float*)d_in[10];
    const float* Wf  = (const float*)d_in[11];
    const float* bf  = (const float*)d_in[12];
    float* out = (float*)d_out;
    _Float16* Wc = (_Float16*)d_ws;    // 4 * 65536 f16 = 512 KB

    convert_weights<<<1024, 256, 0, stream>>>(W1, W2, W3, W4, Wc);

    const int N = in_sizes[0] / 3;     // 1048576
    siren_fused<<<N / NPB, THREADS, 0, stream>>>(
        xyt, W0, b0, Wc, b1, b2, b3, b4, Wf, bf, out);
}